// Round 5
// baseline (27946.506 us; speedup 1.0000x reference)
//
#include <hip/hip_runtime.h>
#include <math.h>

#define DEV __device__ __forceinline__

constexpr int B = 8, T = 128, V = 32000, A = 64, D = 256, NS = 16, S = 128, H = 4, HD = 64;
constexpr int D2 = 512;

DEV float sigm(float x) { return 1.0f / (1.0f + expf(-x)); }
DEV float geluf(float x) { return 0.5f * x * (1.0f + erff(x * 0.7071067811865476f)); }

DEV float4 f4z() { return make_float4(0.f, 0.f, 0.f, 0.f); }
DEV float4 ld4(const float* s) { return *(const float4*)s; }
DEV void st4(float* d, float4 v) { *(float4*)d = v; }
DEV float4 fma4(float a, float4 b, float4 c) {
  c.x += a * b.x; c.y += a * b.y; c.z += a * b.z; c.w += a * b.w; return c;
}
DEV float4 add4(float4 a, float4 b) {
  a.x += b.x; a.y += b.y; a.z += b.z; a.w += b.w; return a;
}
DEV float4 shflx4(float4 v, int m) {
  v.x = __shfl_xor(v.x, m, 64); v.y = __shfl_xor(v.y, m, 64);
  v.z = __shfl_xor(v.z, m, 64); v.w = __shfl_xor(v.w, m, 64); return v;
}

// -------- coherent (agent-scope atomic) 8-byte accessors: NO fences needed --------
DEV void ast8(float* p, float x, float y) {
  union { float f[2]; unsigned long long u; } v;
  v.f[0] = x; v.f[1] = y;
  __hip_atomic_store((unsigned long long*)p, v.u, __ATOMIC_RELAXED, __HIP_MEMORY_SCOPE_AGENT);
}
DEV float2 ald8(const float* p) {
  unsigned long long u =
      __hip_atomic_load((const unsigned long long*)p, __ATOMIC_RELAXED, __HIP_MEMORY_SCOPE_AGENT);
  union { unsigned long long u; float f[2]; } v;
  v.u = u;
  return make_float2(v.f[0], v.f[1]);
}

// ---------------- setup kernels ----------------

__global__ __launch_bounds__(256) void k_setup(const float* __restrict__ aimp,
                                               const float* __restrict__ cmix,
                                               const float* __restrict__ bind,
                                               const float* __restrict__ bsens,
                                               float* __restrict__ iw, float* __restrict__ cwv,
                                               float* __restrict__ sigbind,
                                               float* __restrict__ bs2) {
  int tid = threadIdx.x;
  if (tid < 64) {
    float v = aimp[tid];
    float m = v;
    #pragma unroll
    for (int o = 32; o > 0; o >>= 1) m = fmaxf(m, __shfl_xor(m, o, 64));
    float e = expf(v - m);
    float s = e;
    #pragma unroll
    for (int o = 32; o > 0; o >>= 1) s += __shfl_xor(s, o, 64);
    iw[tid] = e / s;
  }
  if (tid == 0) {
    float a = cmix[0], b = cmix[1], m = fmaxf(a, b);
    float ea = expf(a - m), eb = expf(b - m);
    cwv[0] = ea / (ea + eb);
    cwv[1] = eb / (ea + eb);
  }
  for (int i = tid; i < NS * D; i += 256) {
    float sb = sigm(bind[i]);
    sigbind[i] = sb;
    bs2[i] = bsens[i] * sb;
  }
}

__global__ __launch_bounds__(256) void k_percepts(const int* __restrict__ idx,
                                                  const float* __restrict__ emb,
                                                  const float* __restrict__ pos,
                                                  float* __restrict__ P) {
  int i = blockIdx.x * 256 + threadIdx.x;
  if (i < B * T * D) {
    int d = i & (D - 1);
    int bt = i / D;
    int t = bt & (T - 1);
    P[i] = emb[(size_t)idx[bt] * D + d] + pos[t * D + d];
  }
}

__global__ __launch_bounds__(256) void k_cvec_part(const float* __restrict__ Wfb,
                                                   const float* __restrict__ ba2,
                                                   float* __restrict__ part) {
  int p = blockIdx.x, tid = threadIdx.x;
  int v0 = p * 256;
  float acc = 0.f;
  for (int vv = 0; vv < 256; vv++) acc += ba2[v0 + vv] * Wfb[(size_t)(v0 + vv) * D + tid];
  part[p * 256 + tid] = acc;
}

__global__ __launch_bounds__(256) void k_cvec_red(const float* __restrict__ part,
                                                  const float* __restrict__ bfb,
                                                  float* __restrict__ cvec) {
  int tid = threadIdx.x;
  float s = 0.f;
  for (int p = 0; p < 125; p++) s += part[p * 256 + tid];
  cvec[tid] = s + bfb[tid];
}

__global__ __launch_bounds__(256) void k_mpart(const float* __restrict__ Wa2,
                                               const float* __restrict__ Wfb,
                                               float* __restrict__ part) {
  int it = blockIdx.y;
  int vc = blockIdx.x;
  int j = threadIdx.x;
  int i0 = it * 32, v0 = vc * 4000;
  __shared__ float a_l[32 * 125];
  float acc[32];
  #pragma unroll
  for (int r = 0; r < 32; r++) acc[r] = 0.f;
  for (int vb = 0; vb < 4000; vb += 125) {
    for (int l = threadIdx.x; l < 32 * 125; l += 256) {
      int r = l / 125, c = l - r * 125;
      a_l[l] = Wa2[(size_t)(i0 + r) * V + v0 + vb + c];
    }
    __syncthreads();
    for (int c = 0; c < 125; c++) {
      float w = Wfb[(size_t)(v0 + vb + c) * D + j];
      #pragma unroll
      for (int r = 0; r < 32; r++) acc[r] += a_l[r * 125 + c] * w;
    }
    __syncthreads();
  }
  for (int r = 0; r < 32; r++) part[((size_t)vc * D2 + i0 + r) * D + j] = acc[r];
}

__global__ __launch_bounds__(256) void k_mreduce(const float* __restrict__ part,
                                                 float* __restrict__ M) {
  int i = blockIdx.x, j = threadIdx.x;
  float s = 0.f;
  for (int vc = 0; vc < 8; vc++) s += part[((size_t)vc * D2 + i) * D + j];
  M[i * D + j] = s;
}

__global__ __launch_bounds__(256) void k_gemmK256(const float* __restrict__ Am,
                                                  const float* __restrict__ Bm,
                                                  float* __restrict__ C, int I) {
  int r0 = blockIdx.x * 8;
  int tid = threadIdx.x;
  __shared__ float a_l[8][256];
  for (int i = tid; i < 8 * 256; i += 256) a_l[i >> 8][i & 255] = Am[(r0 + (i >> 8)) * 256 + (i & 255)];
  __syncthreads();
  float acc[8] = {0, 0, 0, 0, 0, 0, 0, 0};
  for (int k = 0; k < 256; k++) {
    float bv = Bm[k * 256 + tid];
    #pragma unroll
    for (int r = 0; r < 8; r++) acc[r] += a_l[r][k] * bv;
  }
  for (int r = 0; r < 8; r++) C[(r0 + r) * 256 + tid] = acc[r];
}

__global__ __launch_bounds__(256) void k_vecmat(const float* __restrict__ a,
                                                const float* __restrict__ Bm,
                                                const float* __restrict__ bias,
                                                float* __restrict__ out) {
  int tid = threadIdx.x;
  __shared__ float a_l[256];
  a_l[tid] = a[tid];
  __syncthreads();
  float acc = 0.f;
  for (int k = 0; k < 256; k++) acc += a_l[k] * Bm[k * 256 + tid];
  out[tid] = acc + bias[tid];
}

__global__ __launch_bounds__(256) void k_barinit(unsigned* bars) {
  int i = blockIdx.x * 256 + threadIdx.x;
  if (i < 8192) bars[i] = 0u;
}

// ---------------- chain barrier (32 blocks, flag-array, fence-free) ----------------

DEV void cbar(unsigned* f, int slot, unsigned e) {
  __syncthreads();  // compiler drains vmcnt(0) before s_barrier -> all our atomic stores visible
  if (threadIdx.x == 0) {
    asm volatile("s_waitcnt vmcnt(0) lgkmcnt(0)" ::: "memory");
    __hip_atomic_store(&f[slot * 32], e, __ATOMIC_RELAXED, __HIP_MEMORY_SCOPE_AGENT);
  }
  if (threadIdx.x < 64) {
    int s = threadIdx.x & 31;
    unsigned spins = 0;
    for (;;) {
      unsigned v = __hip_atomic_load(&f[s * 32], __ATOMIC_RELAXED, __HIP_MEMORY_SCOPE_AGENT);
      if (__all(v >= e)) break;
      __builtin_amdgcn_s_sleep(1);
      if (++spins > (1u << 25)) break;
    }
  }
  __syncthreads();
}

// ---------------- persistent kernel ----------------

struct PP {
  const float *Wsens, *bs2, *sigbind, *anet, *Wc, *bc, *Wg, *bg, *lng, *lnb, *cw, *iw;
  const float *Wq, *bq, *Wk, *bk, *Wv, *bv, *Wo, *bo, *Wmg, *WoMg, *cvec2, *mlng, *mlnb;
  const float *Wa1, *ba1, *M2, *cvec3, *cvec4, *P, *pW;
  float *agents, *sensbuf, *ubufG, *psumU, *consbuf, *recbuf, *valbuf, *valps;
  float *kvK, *kvV, *hbuf, *modbuf, *Hall;
  unsigned* flags;
};

// LDS layout (floats):
#define A_OFF 0        // [32][257] = 8224
#define ASL_OFF 8224   // [64][16]  = 1024
#define X_OFF 9248     // [64][48]  = 3072  (U1 in P3)
#define U_OFF 12320    // [64][16]  = 1024
#define MOD_OFF 13344  // 256
#define CONS_OFF 13600 // 256
#define REC_OFF 13856  // 256 (scores/probs in P4)
#define VV_OFF 14112   // 256 (q in P4, val in P5/P6)
#define CF_OFF 14368   // 256
#define HL_OFF 14624   // 512
#define STT_OFF 15136  // 256
#define RED_OFF 15392  // 1024
#define K_OFF 16416    // [128][65] = 8320
#define V_OFF 24736    // [128][64] = 8192
#define TOTAL_LDS_F 32928  // 131712 bytes

__global__ __launch_bounds__(512) void k_persist(PP p) {
  extern __shared__ float sm[];
  const int bid = blockIdx.x;
  const int tid = threadIdx.x;
  const int b = bid & 7;       // chain (batch)
  const int slot = bid >> 3;   // 0..31 within chain
  const int ch = slot >> 4;    // G1 channel
  const int i16 = slot & 15;   // G1 16-col slice
  const int d0 = i16 * 16;
  unsigned* flg = p.flags + b * 1024;
  unsigned e = 1;

  float* A_l = sm + A_OFF;
  float* Asl = sm + ASL_OFF;
  float* X_l = sm + X_OFF;
  float* U_l = sm + U_OFF;
  float* MODL = sm + MOD_OFF;
  float* CONSL = sm + CONS_OFF;
  float* RECL = sm + REC_OFF;
  float* VVL = sm + VV_OFF;
  float* CFL = sm + CF_OFF;
  float* HLL = sm + HL_OFF;
  float* STT = sm + STT_OFF;
  float* RED = sm + RED_OFF;
  float* K_l = sm + K_OFF;
  float* V_l = sm + V_OFF;

  // ---------- INIT: zero agents slice; mod0 slice ----------
  if (tid < 256) ast8(p.agents + b * 16384 + slot * 512 + tid * 2, 0.f, 0.f);
  if (tid < 4) {
    int c = slot * 8 + tid * 2;
    int o = (b * 128) * 256 + c;
    float m0 = p.P[o] * (1.f + sigm(p.cvec4[c] + p.pW[o]));
    float m1 = p.P[o + 1] * (1.f + sigm(p.cvec4[c + 1] + p.pW[o + 1]));
    ast8(p.modbuf + b * 256 + c, m0, m1);
  }
  cbar(flg, slot, e); e++;

  for (int t = 0; t < T; t++) {
    // ======== P1: stage mod; sens slice (128 cols); att blocks pull K/V slot t-1 ========
    {
      if (tid < 128) {
        float2 v = ald8(p.modbuf + b * 256 + tid * 2);
        MODL[tid * 2] = v.x; MODL[tid * 2 + 1] = v.y;
      }
      if (slot < 4 && t >= 1) {
        if (tid >= 128 && tid < 160) {
          int i2 = (tid - 128) * 2;
          float2 v = ald8(p.kvK + b * 256 + slot * 64 + i2);
          K_l[(t - 1) * 65 + i2] = v.x; K_l[(t - 1) * 65 + i2 + 1] = v.y;
        } else if (tid >= 160 && tid < 192) {
          int i2 = (tid - 160) * 2;
          float2 v = ald8(p.kvV + b * 256 + slot * 64 + i2);
          V_l[(t - 1) * 64 + i2] = v.x; V_l[(t - 1) * 64 + i2 + 1] = v.y;
        }
      }
      __syncthreads();
      {
        int cc = tid & 127, ks = tid >> 7;
        int col = slot * 128 + cc;
        float acc = 0.f;
        #pragma unroll 16
        for (int kk = 0; kk < 64; kk++) {
          int k = ks + kk * 4;
          acc += MODL[k] * p.Wsens[k * 4096 + col];
        }
        RED[ks * 128 + cc] = acc;
      }
      __syncthreads();
      if (tid < 64) {
        int c2 = tid * 2;
        int col = slot * 128 + c2;
        float s0 = RED[c2] + RED[128 + c2] + RED[256 + c2] + RED[384 + c2];
        float s1 = RED[c2 + 1] + RED[128 + c2 + 1] + RED[256 + c2 + 1] + RED[384 + c2 + 1];
        ast8(p.sensbuf + b * 4096 + col,
             s0 * p.sigbind[col] + p.bs2[col],
             s1 * p.sigbind[col + 1] + p.bs2[col + 1]);
      }
    }
    cbar(flg, slot, e); e++;

    // ======== P2: A-stage (2 halves) -> X -> Y -> u -> psums (+ch1 u export) ========
    {
      for (int half = 0; half < 2; half++) {
        for (int u = tid; u < 4096; u += 512) {
          int gu = half * 4096 + u;
          float2 v = ald8(p.agents + b * 16384 + gu * 2);
          if (half == 0 && u < 2048) {
            float2 s = ald8(p.sensbuf + b * 4096 + u * 2);
            v.x += s.x; v.y += s.y;
          }
          int r = u >> 7, kp = (u & 127) * 2;
          A_l[r * 257 + kp] = v.x; A_l[r * 257 + kp + 1] = v.y;
        }
        __syncthreads();
        {
          int r = tid >> 4, dc = tid & 15;
          Asl[(half * 32 + r) * 16 + dc] = A_l[r * 257 + d0 + dc];
        }
        {
          int r = tid >> 4, dq = (tid >> 2) & 3, ks = tid & 3;
          float4 ac = f4z(), ag0 = f4z(), ag1 = f4z();
          const float* wc = p.Wc + ch * 65536 + d0 + dq * 4;
          const float* wg0 = p.Wg + ch * 131072 + d0 + dq * 4;
          const float* wg1 = wg0 + 65536;
          #pragma unroll 8
          for (int kk = 0; kk < 64; kk++) {
            int k = ks + kk * 4;
            float a = A_l[r * 257 + k];
            ac = fma4(a, ld4(wc + k * 256), ac);
            ag0 = fma4(a, ld4(wg0 + k * 256), ag0);
            ag1 = fma4(a, ld4(wg1 + k * 256), ag1);
          }
          ac = add4(ac, shflx4(ac, 1)); ag0 = add4(ag0, shflx4(ag0, 1)); ag1 = add4(ag1, shflx4(ag1, 1));
          ac = add4(ac, shflx4(ac, 2)); ag0 = add4(ag0, shflx4(ag0, 2)); ag1 = add4(ag1, shflx4(ag1, 2));
          if (ks == 0) {
            int rr = half * 32 + r;
            st4(&X_l[rr * 48 + dq * 4], ac);
            st4(&X_l[rr * 48 + 16 + dq * 4], ag0);
            st4(&X_l[rr * 48 + 32 + dq * 4], ag1);
          }
        }
        __syncthreads();
      }
      // Y + u
      {
        int r = tid >> 3, dq = (tid >> 1) & 3, js = tid & 1;
        float4 yc = f4z(), yg = f4z();
        const float* an = p.anet + ch * 4096 + r * 64;
        #pragma unroll 8
        for (int jj = 0; jj < 32; jj++) {
          int j = js + jj * 2;
          float a = an[j];
          yc = fma4(a, ld4(&X_l[j * 48 + dq * 4]), yc);
          yg = fma4(a, ld4(&X_l[j * 48 + 32 + dq * 4]), yg);
        }
        yc = add4(yc, shflx4(yc, 1));
        yg = add4(yg, shflx4(yg, 1));
        float su = 0.f, sq = 0.f;
        if (js == 0) {
          int c0g = d0 + dq * 4;
          float4 xg0 = ld4(&X_l[r * 48 + 16 + dq * 4]);
          float4 av = ld4(&Asl[r * 16 + dq * 4]);
          float4 bc4 = ld4(p.bc + ch * 256 + c0g);
          float4 bg4 = ld4(p.bg + ch * 256 + c0g);
          float4 uu;
          {
            float g0 = sigm(xg0.x + yg.x + bg4.x), c0c = geluf(yc.x + bc4.x);
            uu.x = g0 * c0c + (1.f - g0) * av.x;
            float g1 = sigm(xg0.y + yg.y + bg4.y), c1c = geluf(yc.y + bc4.y);
            uu.y = g1 * c1c + (1.f - g1) * av.y;
            float g2 = sigm(xg0.z + yg.z + bg4.z), c2c = geluf(yc.z + bc4.z);
            uu.z = g2 * c2c + (1.f - g2) * av.z;
            float g3 = sigm(xg0.w + yg.w + bg4.w), c3c = geluf(yc.w + bc4.w);
            uu.w = g3 * c3c + (1.f - g3) * av.w;
          }
          st4(&U_l[r * 16 + dq * 4], uu);
          su = uu.x + uu.y + uu.z + uu.w;
          sq = uu.x * uu.x + uu.y * uu.y + uu.z * uu.z + uu.w * uu.w;
        }
        su += __shfl_xor(su, 2, 64); sq += __shfl_xor(sq, 2, 64);
        su += __shfl_xor(su, 4, 64); sq += __shfl_xor(sq, 4, 64);
        if ((tid & 7) == 0)
          ast8(p.psumU + (((b * 2 + ch) * 16 + i16) * 64 + r) * 2, su, sq);
      }
      __syncthreads();
      if (ch == 1) {
        int r = tid >> 3, pp2 = tid & 7;
        ast8(p.ubufG + (((b * 16 + i16) * 64 + r) * 16) + pp2 * 2,
             U_l[r * 16 + pp2 * 2], U_l[r * 16 + pp2 * 2 + 1]);
      }
    }
    cbar(flg, slot, e); e++;

    // ======== P3 (ch0 slots): LN stats, mix -> agents + cons ========
    if (ch == 0) {
      {
        int r = tid >> 3, pp2 = tid & 7;
        float2 v = ald8(p.ubufG + (((b * 16 + i16) * 64 + r) * 16) + pp2 * 2);
        X_l[r * 16 + pp2 * 2] = v.x; X_l[r * 16 + pp2 * 2 + 1] = v.y;  // U1
      }
      if (tid < 128) {
        int ch2 = tid >> 6, r = tid & 63;
        float s = 0.f, q = 0.f;
        #pragma unroll
        for (int blk = 0; blk < 16; blk++) {
          float2 v = ald8(p.psumU + (((b * 2 + ch2) * 16 + blk) * 64 + r) * 2);
          s += v.x; q += v.y;
        }
        float mn = s * (1.f / 256.f), var = q * (1.f / 256.f) - mn * mn;
        STT[(ch2 * 64 + r) * 2] = mn;
        STT[(ch2 * 64 + r) * 2 + 1] = rsqrtf(var + 1e-5f);
      }
      __syncthreads();
      {
        float cw0 = p.cw[0], cw1 = p.cw[1];
        int r = tid >> 3, pp2 = tid & 7;
        int c0g = d0 + pp2 * 2;
        float m0 = STT[r * 2], rs0 = STT[r * 2 + 1];
        float m1 = STT[128 + r * 2], rs1 = STT[128 + r * 2 + 1];
        float u0a = U_l[r * 16 + pp2 * 2], u0b = U_l[r * 16 + pp2 * 2 + 1];
        float u1a = X_l[r * 16 + pp2 * 2], u1b = X_l[r * 16 + pp2 * 2 + 1];
        float na = cw0 * ((u0a - m0) * rs0 * p.lng[c0g] + p.lnb[c0g]) +
                   cw1 * ((u1a - m1) * rs1 * p.lng[256 + c0g] + p.lnb[256 + c0g]);
        float nb = cw0 * ((u0b - m0) * rs0 * p.lng[c0g + 1] + p.lnb[c0g + 1]) +
                   cw1 * ((u1b - m1) * rs1 * p.lng[256 + c0g + 1] + p.lnb[256 + c0g + 1]);
        ast8(p.agents + (b * 64 + r) * 256 + c0g, na, nb);
        float iwr = p.iw[r];
        float pa = iwr * na, pb = iwr * nb;
        pa += __shfl_xor(pa, 8, 64); pb += __shfl_xor(pb, 8, 64);
        pa += __shfl_xor(pa, 16, 64); pb += __shfl_xor(pb, 16, 64);
        pa += __shfl_xor(pa, 32, 64); pb += __shfl_xor(pb, 32, 64);
        if ((tid & 63) < 8) {
          RED[(tid >> 6) * 8 + (tid & 7)] = pa;
          RED[64 + (tid >> 6) * 8 + (tid & 7)] = pb;
        }
      }
      __syncthreads();
      if (tid < 8) {
        float sa = 0.f, sb = 0.f;
        #pragma unroll
        for (int w = 0; w < 8; w++) { sa += RED[w * 8 + tid]; sb += RED[64 + w * 8 + tid]; }
        ast8(p.consbuf + b * 256 + d0 + tid * 2, sa, sb);
      }
    }
    cbar(flg, slot, e); e++;

    // ======== P4 (slots 0-3 = heads): q, scores, softmax, rec ========
    if (slot < 4 && t > 0) {
      int h = slot;
      if (tid < 128) {
        float2 v = ald8(p.consbuf + b * 256 + tid * 2);
        CONSL[tid * 2] = v.x; CONSL[tid * 2 + 1] = v.y;
      }
      __syncthreads();
      {
        int c = tid & 63, ks = tid >> 6;
        float acc = 0.f;
        #pragma unroll 8
        for (int kk = 0; kk < 32; kk++) {
          int k = ks + kk * 8;
          acc += CONSL[k] * p.Wq[k * 256 + h * 64 + c];
        }
        RED[ks * 64 + c] = acc;
      }
      __syncthreads();
      if (tid < 64) {
        float qv = p.bq[h * 64 + tid];
        #pragma unroll
        for (int w = 0; w < 8; w++) qv += RED[w * 64 + tid];
        VVL[tid] = qv;
      }
      __syncthreads();
      {
        int s = tid >> 2, ds = tid & 3;
        float acc = 0.f;
        if (s < t) {
          #pragma unroll
          for (int i2 = 0; i2 < 16; i2++) {
            int d = ds * 16 + i2;
            acc += VVL[d] * K_l[s * 65 + d];
          }
        }
        acc += __shfl_xor(acc, 1, 64);
        acc += __shfl_xor(acc, 2, 64);
        if (s < t && ds == 0) RECL[s] = acc * 0.125f;
      }
      __syncthreads();
      if (tid < 128) {
        float v = (tid < t) ? RECL[tid] : -1e30f;
        float m = v;
        #pragma unroll
        for (int o = 1; o < 64; o <<= 1) m = fmaxf(m, __shfl_xor(m, o, 64));
        if ((tid & 63) == 0) STT[tid >> 6] = m;
      }
      __syncthreads();
      if (tid < 128) {
        float m = fmaxf(STT[0], STT[1]);
        float v = (tid < t) ? RECL[tid] : -1e30f;
        float ee = (tid < t) ? expf(v - m) : 0.f;
        float den = ee;
        #pragma unroll
        for (int o = 1; o < 64; o <<= 1) den += __shfl_xor(den, o, 64);
        if ((tid & 63) == 0) STT[2 + (tid >> 6)] = den;
        CFL[tid] = ee;
      }
      __syncthreads();
      if (tid < 128) RECL[tid] = CFL[tid] / (STT[2] + STT[3]);
      __syncthreads();
      {
        int c = tid & 63, ss = tid >> 6;
        float acc = 0.f;
        #pragma unroll
        for (int i2 = 0; i2 < 16; i2++) {
          int s = ss + i2 * 8;
          if (s < t) acc += RECL[s] * V_l[s * 64 + c];
        }
        RED[ss * 64 + c] = acc;
      }
      __syncthreads();
      if (tid < 64) {
        float rv = 0.f;
        #pragma unroll
        for (int w = 0; w < 8; w++) rv += RED[w * 64 + tid];
        CFL[tid] = rv;
      }
      __syncthreads();
      if (tid < 32) ast8(p.recbuf + b * 256 + h * 64 + tid * 2, CFL[tid * 2], CFL[tid * 2 + 1]);
    }
    cbar(flg, slot, e); e++;

    // ======== P5 (slots 8-15): o / mg / val / valps ========
    if (slot >= 8 && slot < 16 && t > 0) {
      int j = slot - 8;
      if (tid < 128) {
        float2 v = ald8(p.recbuf + b * 256 + tid * 2);
        RECL[tid * 2] = v.x; RECL[tid * 2 + 1] = v.y;
        float2 w = ald8(p.consbuf + b * 256 + tid * 2);
        CONSL[tid * 2] = w.x; CONSL[tid * 2 + 1] = w.y;
      }
      __syncthreads();
      {
        int c = tid & 31, ks = tid >> 5;
        float po = 0.f, pm = 0.f;
        #pragma unroll
        for (int kk = 0; kk < 16; kk++) {
          int k = ks + kk * 16;
          float rv = RECL[k], cv = CONSL[k];
          po += rv * p.Wo[k * 256 + j * 32 + c];
          pm += cv * p.Wmg[k * 256 + j * 32 + c] + rv * p.WoMg[k * 256 + j * 32 + c];
        }
        RED[ks * 32 + c] = po;
        RED[512 + ks * 32 + c] = pm;
      }
      __syncthreads();
      if (tid < 32) {
        int col = j * 32 + tid;
        float so = p.bo[col], sm2 = p.cvec2[col];
        #pragma unroll
        for (int k2 = 0; k2 < 16; k2++) { so += RED[k2 * 32 + tid]; sm2 += RED[512 + k2 * 32 + tid]; }
        float mg = sigm(sm2);
        float val = CONSL[col] + mg * so;
        VVL[tid] = val;
        float su = val, sq = val * val;
        #pragma unroll
        for (int o2 = 1; o2 <= 16; o2 <<= 1) { su += __shfl_xor(su, o2, 64); sq += __shfl_xor(sq, o2, 64); }
        if (tid == 0) ast8(p.valps + (b * 8 + j) * 2, su, sq);
      }
      __syncthreads();
      if (tid < 16) ast8(p.valbuf + b * 256 + j * 32 + tid * 2, VVL[tid * 2], VVL[tid * 2 + 1]);
    }
    cbar(flg, slot, e); e++;

    // ======== P6 (slots 16-23): cf (redundant LN) -> K/V -> h ========
    if (slot >= 16 && slot < 24) {
      int jj = slot - 16;
      const float* src = (t > 0) ? p.valbuf : p.consbuf;
      if (tid < 128) {
        float2 v = ald8(src + b * 256 + tid * 2);
        VVL[tid * 2] = v.x; VVL[tid * 2 + 1] = v.y;
      }
      if (t > 0 && tid >= 128 && tid < 136) {
        float2 v = ald8(p.valps + (b * 8 + (tid - 128)) * 2);
        RED[(tid - 128) * 2] = v.x; RED[(tid - 128) * 2 + 1] = v.y;
      }
      __syncthreads();
      if (t > 0) {
        if (tid == 0) {
          float s = 0.f, q = 0.f;
          #pragma unroll
          for (int k2 = 0; k2 < 8; k2++) { s += RED[k2 * 2]; q += RED[k2 * 2 + 1]; }
          float mn = s * (1.f / 256.f), var = q * (1.f / 256.f) - mn * mn;
          STT[0] = mn; STT[1] = rsqrtf(var + 1e-5f);
        }
        __syncthreads();
        if (tid < 256) CFL[tid] = (VVL[tid] - STT[0]) * STT[1] * p.mlng[tid] + p.mlnb[tid];
      } else {
        if (tid < 256) CFL[tid] = VVL[tid];
      }
      __syncthreads();
      {
        int c = tid & 31, ks = tid >> 5;
        float pk = 0.f, pv = 0.f;
        #pragma unroll
        for (int kk = 0; kk < 16; kk++) {
          int k = ks + kk * 16;
          float cf = CFL[k];
          pk += cf * p.Wk[k * 256 + jj * 32 + c];
          pv += cf * p.Wv[k * 256 + jj * 32 + c];
        }
        RED[ks * 32 + c] = pk;
        RED[512 + ks * 32 + c] = pv;
      }
      __syncthreads();
      if (tid < 32) {
        int col = jj * 32 + tid;
        float sk = p.bk[col], sv = p.bv[col];
        #pragma unroll
        for (int k2 = 0; k2 < 16; k2++) { sk += RED[k2 * 32 + tid]; sv += RED[512 + k2 * 32 + tid]; }
        VVL[tid] = sk;
        VVL[64 + tid] = sv;
      }
      __syncthreads();
      if (tid < 16) {
        ast8(p.kvK + b * 256 + jj * 32 + tid * 2, VVL[tid * 2], VVL[tid * 2 + 1]);
        ast8(p.kvV + b * 256 + jj * 32 + tid * 2, VVL[64 + tid * 2], VVL[64 + tid * 2 + 1]);
      }
      __syncthreads();
      {
        int c = tid & 63, ks = tid >> 6;
        float ph = 0.f;
        #pragma unroll 8
        for (int kk = 0; kk < 32; kk++) {
          int k = ks + kk * 8;
          ph += CFL[k] * p.Wa1[k * 512 + jj * 64 + c];
        }
        RED[ks * 64 + c] = ph;
      }
      __syncthreads();
      if (tid < 64) {
        int col = jj * 64 + tid;
        float s = p.ba1[col];
        #pragma unroll
        for (int w = 0; w < 8; w++) s += RED[w * 64 + tid];
        float hv = geluf(s);
        HLL[tid] = hv;
        p.Hall[(size_t)(b * 128 + t) * 512 + col] = hv;  // plain: read post-kernel only
      }
      __syncthreads();
      if (tid < 32) ast8(p.hbuf + b * 512 + jj * 64 + tid * 2, HLL[tid * 2], HLL[tid * 2 + 1]);
    }
    cbar(flg, slot, e); e++;

    // ======== P7 (slots 24-31): fg -> mod ========
    if (slot >= 24 && t < T - 1) {
      int jm = slot - 24;
      if (tid < 256) {
        float2 v = ald8(p.hbuf + b * 512 + tid * 2);
        HLL[tid * 2] = v.x; HLL[tid * 2 + 1] = v.y;
      }
      __syncthreads();
      {
        int c = tid & 31, ks = tid >> 5;
        float pf = 0.f;
        #pragma unroll 8
        for (int kk = 0; kk < 32; kk++) {
          int k = ks + kk * 16;
          pf += HLL[k] * p.M2[k * 256 + jm * 32 + c];
        }
        RED[ks * 32 + c] = pf;
      }
      __syncthreads();
      if (tid < 32) {
        int col = jm * 32 + tid;
        float s = p.cvec3[col];
        #pragma unroll
        for (int k2 = 0; k2 < 16; k2++) s += RED[k2 * 32 + tid];
        int o = (b * 128 + t + 1) * 256 + col;
        VVL[tid] = p.P[o] * (1.f + sigm(s + p.pW[o]));
      }
      __syncthreads();
      if (tid < 16) ast8(p.modbuf + b * 256 + jm * 32 + tid * 2, VVL[tid * 2], VVL[tid * 2 + 1]);
    }
    cbar(flg, slot, e); e++;
  }
}

// ---------------- logits ----------------

__global__ __launch_bounds__(256) void k_logits(const float* __restrict__ Hall,
                                                const float* __restrict__ Wa2,
                                                const float* __restrict__ ba2,
                                                float* __restrict__ out) {
  int rt = blockIdx.y;
  int v = blockIdx.x * 256 + threadIdx.x;
  const float* hrow = Hall + (size_t)rt * 32 * D2;
  float acc[32];
  float bb = ba2[v];
  #pragma unroll
  for (int r = 0; r < 32; r++) acc[r] = bb;
  for (int k = 0; k < D2; k++) {
    float w = Wa2[(size_t)k * V + v];
    #pragma unroll
    for (int r = 0; r < 32; r++) acc[r] += hrow[r * D2 + k] * w;
  }
  for (int r = 0; r < 32; r++) out[(size_t)(rt * 32 + r) * V + v] = acc[r];
}

// ---------------- launcher ----------------

extern "C" void kernel_launch(void* const* d_in, const int* in_sizes, int n_in,
                              void* d_out, int out_size, void* d_ws, size_t ws_size,
                              hipStream_t stream) {
  const int* idx = (const int*)d_in[0];
  const float* emb = (const float*)d_in[1];
  const float* pos = (const float*)d_in[2];
  const float* Wsens = (const float*)d_in[3];
  const float* bsens = (const float*)d_in[4];
  const float* Wfb = (const float*)d_in[5];
  const float* bfb = (const float*)d_in[6];
  const float* Wfg = (const float*)d_in[7];
  const float* bfg = (const float*)d_in[8];
  const float* bind = (const float*)d_in[9];
  const float* anet = (const float*)d_in[10];
  const float* Wg = (const float*)d_in[11];
  const float* bg = (const float*)d_in[12];
  const float* Wc = (const float*)d_in[13];
  const float* bc = (const float*)d_in[14];
  const float* lng = (const float*)d_in[15];
  const float* lnb = (const float*)d_in[16];
  const float* cmix = (const float*)d_in[17];
  const float* aimp = (const float*)d_in[18];
  const float* Wq = (const float*)d_in[19];
  const float* bq = (const float*)d_in[20];
  const float* Wk = (const float*)d_in[21];
  const float* bk = (const float*)d_in[22];
  const float* Wv = (const float*)d_in[23];
  const float* bv = (const float*)d_in[24];
  const float* Wo = (const float*)d_in[25];
  const float* bo = (const float*)d_in[26];
  const float* Wmg = (const float*)d_in[27];
  const float* bmg = (const float*)d_in[28];
  const float* mlng = (const float*)d_in[29];
  const float* mlnb = (const float*)d_in[30];
  const float* Wa1 = (const float*)d_in[31];
  const float* ba1 = (const float*)d_in[32];
  const float* Wa2 = (const float*)d_in[33];
  const float* ba2 = (const float*)d_in[34];

  float* ws = (float*)d_ws;
  float* M2 = ws + 0;              // 131072
  float* WoMg = ws + 131072;       // 65536
  float* cvec = ws + 196608;       // 256
  float* cvec2 = ws + 196864;      // 256
  float* cvec3 = ws + 197120;      // 256
  float* cvec4 = ws + 197376;      // 256
  float* iw = ws + 197632;         // 64
  float* cwb = ws + 197696;        // 64
  float* sigbind = ws + 197760;    // 4096
  float* bs2 = ws + 201856;        // 4096
  float* P = ws + 205952;          // 262144
  float* pW = ws + 468096;         // 262144
  float* agents = ws + 730240;     // 131072
  float* sensbuf = ws + 861312;    // 32768
  float* ubufG = ws + 894080;      // 131072
  float* psumU = ws + 1025152;     // 32768
  float* consbuf = ws + 1057920;   // 2048
  float* recbuf = ws + 1059968;    // 2048
  float* valbuf = ws + 1062016;    // 2048
  float* valps = ws + 1064064;     // 128
  float* kvK = ws + 1064192;       // 2048
  float* kvV = ws + 1066240;       // 2048
  float* hbuf = ws + 1068288;      // 4096
  float* modbuf = ws + 1072384;    // 2048
  float* Hall = ws + 1074432;      // 524288
  float* M = ws + 1598720;         // 131072
  float* Mpart = ws + 1729792;     // 1048576
  float* cvpart = ws + 2778368;    // 32000
  unsigned* flags = (unsigned*)(ws + 2810368);  // 8192 u32

  k_setup<<<1, 256, 0, stream>>>(aimp, cmix, bind, bsens, iw, cwb, sigbind, bs2);
  k_percepts<<<dim3((B * T * D + 255) / 256), 256, 0, stream>>>(idx, emb, pos, P);
  k_cvec_part<<<125, 256, 0, stream>>>(Wfb, ba2, cvpart);
  k_cvec_red<<<1, 256, 0, stream>>>(cvpart, bfb, cvec);
  k_mpart<<<dim3(8, 16), 256, 0, stream>>>(Wa2, Wfb, Mpart);
  k_mreduce<<<512, 256, 0, stream>>>(Mpart, M);
  k_gemmK256<<<64, 256, 0, stream>>>(M, Wfg, M2, 512);
  k_gemmK256<<<32, 256, 0, stream>>>(Wo, Wmg + 65536, WoMg, 256);
  k_gemmK256<<<128, 256, 0, stream>>>(P, Wfg + 65536, pW, 1024);
  k_vecmat<<<1, 256, 0, stream>>>(bo, Wmg + 65536, bmg, cvec2);
  k_vecmat<<<1, 256, 0, stream>>>(cvec, Wfg, bfg, cvec3);
  k_vecmat<<<1, 256, 0, stream>>>(bfb, Wfg, bfg, cvec4);
  k_barinit<<<32, 256, 0, stream>>>(flags);

  PP prm;
  prm.Wsens = Wsens; prm.bs2 = bs2; prm.sigbind = sigbind; prm.anet = anet;
  prm.Wc = Wc; prm.bc = bc; prm.Wg = Wg; prm.bg = bg; prm.lng = lng; prm.lnb = lnb;
  prm.cw = cwb; prm.iw = iw; prm.Wq = Wq; prm.bq = bq; prm.Wk = Wk; prm.bk = bk;
  prm.Wv = Wv; prm.bv = bv; prm.Wo = Wo; prm.bo = bo; prm.Wmg = Wmg; prm.WoMg = WoMg;
  prm.cvec2 = cvec2; prm.mlng = mlng; prm.mlnb = mlnb; prm.Wa1 = Wa1; prm.ba1 = ba1;
  prm.M2 = M2; prm.cvec3 = cvec3; prm.cvec4 = cvec4; prm.P = P; prm.pW = pW;
  prm.agents = agents; prm.sensbuf = sensbuf; prm.ubufG = ubufG; prm.psumU = psumU;
  prm.consbuf = consbuf; prm.recbuf = recbuf; prm.valbuf = valbuf; prm.valps = valps;
  prm.kvK = kvK; prm.kvV = kvV; prm.hbuf = hbuf; prm.modbuf = modbuf;
  prm.Hall = Hall; prm.flags = flags;

  hipFuncSetAttribute((const void*)k_persist, hipFuncAttributeMaxDynamicSharedMemorySize,
                      TOTAL_LDS_F * 4);

  void* args[] = {&prm};
  hipLaunchCooperativeKernel((void*)k_persist, dim3(256), dim3(512), args,
                             TOTAL_LDS_F * 4, stream);

  k_logits<<<dim3(125, 32), 256, 0, stream>>>(Hall, Wa2, ba2, (float*)d_out);
}

// Round 6
// 26687.384 us; speedup vs baseline: 1.0472x; 1.0472x over previous
//
#include <hip/hip_runtime.h>
#include <math.h>

#define DEV __device__ __forceinline__

constexpr int B = 8, T = 128, V = 32000, A = 64, D = 256, NS = 16, S = 128, H = 4, HD = 64;
constexpr int D2 = 512;

typedef float f32x4 __attribute__((ext_vector_type(4)));
typedef float f32x2 __attribute__((ext_vector_type(2)));

DEV float sigm(float x) { return 1.0f / (1.0f + expf(-x)); }
DEV float geluf(float x) { return 0.5f * x * (1.0f + erff(x * 0.7071067811865476f)); }

DEV f32x4 f4z() { return f32x4{0.f, 0.f, 0.f, 0.f}; }
DEV f32x4 ld4(const float* s) { return *(const f32x4*)s; }
DEV void st4(float* d, f32x4 v) { *(f32x4*)d = v; }
DEV f32x4 fma4(float a, f32x4 b, f32x4 c) { return c + a * b; }
DEV f32x4 add4(f32x4 a, f32x4 b) { return a + b; }
DEV f32x4 shflx4(f32x4 v, int m) {
  v.x = __shfl_xor(v.x, m, 64); v.y = __shfl_xor(v.y, m, 64);
  v.z = __shfl_xor(v.z, m, 64); v.w = __shfl_xor(v.w, m, 64); return v;
}

// ---- device-coherent COALESCED accessors: plain wide ops with sc0 sc1 (bypass L1+L2) ----
DEV f32x4 cld4(const float* p) {
  f32x4 r;
  asm volatile("global_load_dwordx4 %0, %1, off sc0 sc1\n"
               "s_waitcnt vmcnt(0)"
               : "=&v"(r) : "v"(p) : "memory");
  return r;
}
DEV void cld4x2(const float* p0, const float* p1, f32x4& a, f32x4& b) {
  asm volatile("global_load_dwordx4 %0, %2, off sc0 sc1\n"
               "global_load_dwordx4 %1, %3, off sc0 sc1\n"
               "s_waitcnt vmcnt(0)"
               : "=&v"(a), "=&v"(b) : "v"(p0), "v"(p1) : "memory");
}
DEV void cld4x4(const float* p0, const float* p1, const float* p2, const float* p3,
                f32x4& a, f32x4& b, f32x4& c, f32x4& d) {
  asm volatile("global_load_dwordx4 %0, %4, off sc0 sc1\n"
               "global_load_dwordx4 %1, %5, off sc0 sc1\n"
               "global_load_dwordx4 %2, %6, off sc0 sc1\n"
               "global_load_dwordx4 %3, %7, off sc0 sc1\n"
               "s_waitcnt vmcnt(0)"
               : "=&v"(a), "=&v"(b), "=&v"(c), "=&v"(d)
               : "v"(p0), "v"(p1), "v"(p2), "v"(p3) : "memory");
}
DEV void cst4(float* p, f32x4 v) {
  asm volatile("global_store_dwordx4 %0, %1, off sc0 sc1" :: "v"(p), "v"(v) : "memory");
}
DEV void cst2(float* p, f32x2 v) {
  asm volatile("global_store_dwordx2 %0, %1, off sc0 sc1" :: "v"(p), "v"(v) : "memory");
}

// ---------------- setup kernels ----------------

__global__ __launch_bounds__(256) void k_setup(const float* __restrict__ aimp,
                                               const float* __restrict__ cmix,
                                               const float* __restrict__ bind,
                                               const float* __restrict__ bsens,
                                               float* __restrict__ iw, float* __restrict__ cwv,
                                               float* __restrict__ sigbind,
                                               float* __restrict__ bs2) {
  int tid = threadIdx.x;
  if (tid < 64) {
    float v = aimp[tid];
    float m = v;
    #pragma unroll
    for (int o = 32; o > 0; o >>= 1) m = fmaxf(m, __shfl_xor(m, o, 64));
    float e = expf(v - m);
    float s = e;
    #pragma unroll
    for (int o = 32; o > 0; o >>= 1) s += __shfl_xor(s, o, 64);
    iw[tid] = e / s;
  }
  if (tid == 0) {
    float a = cmix[0], b = cmix[1], m = fmaxf(a, b);
    float ea = expf(a - m), eb = expf(b - m);
    cwv[0] = ea / (ea + eb);
    cwv[1] = eb / (ea + eb);
  }
  for (int i = tid; i < NS * D; i += 256) {
    float sb = sigm(bind[i]);
    sigbind[i] = sb;
    bs2[i] = bsens[i] * sb;
  }
}

__global__ __launch_bounds__(256) void k_percepts(const int* __restrict__ idx,
                                                  const float* __restrict__ emb,
                                                  const float* __restrict__ pos,
                                                  float* __restrict__ P) {
  int i = blockIdx.x * 256 + threadIdx.x;
  if (i < B * T * D) {
    int d = i & (D - 1);
    int bt = i / D;
    int t = bt & (T - 1);
    P[i] = emb[(size_t)idx[bt] * D + d] + pos[t * D + d];
  }
}

__global__ __launch_bounds__(256) void k_cvec_part(const float* __restrict__ Wfb,
                                                   const float* __restrict__ ba2,
                                                   float* __restrict__ part) {
  int p = blockIdx.x, tid = threadIdx.x;
  int v0 = p * 256;
  float acc = 0.f;
  for (int vv = 0; vv < 256; vv++) acc += ba2[v0 + vv] * Wfb[(size_t)(v0 + vv) * D + tid];
  part[p * 256 + tid] = acc;
}

__global__ __launch_bounds__(256) void k_cvec_red(const float* __restrict__ part,
                                                  const float* __restrict__ bfb,
                                                  float* __restrict__ cvec) {
  int tid = threadIdx.x;
  float s = 0.f;
  for (int p = 0; p < 125; p++) s += part[p * 256 + tid];
  cvec[tid] = s + bfb[tid];
}

__global__ __launch_bounds__(256) void k_mpart(const float* __restrict__ Wa2,
                                               const float* __restrict__ Wfb,
                                               float* __restrict__ part) {
  int it = blockIdx.y;
  int vc = blockIdx.x;
  int j = threadIdx.x;
  int i0 = it * 32, v0 = vc * 4000;
  __shared__ float a_l[32 * 125];
  float acc[32];
  #pragma unroll
  for (int r = 0; r < 32; r++) acc[r] = 0.f;
  for (int vb = 0; vb < 4000; vb += 125) {
    for (int l = threadIdx.x; l < 32 * 125; l += 256) {
      int r = l / 125, c = l - r * 125;
      a_l[l] = Wa2[(size_t)(i0 + r) * V + v0 + vb + c];
    }
    __syncthreads();
    for (int c = 0; c < 125; c++) {
      float w = Wfb[(size_t)(v0 + vb + c) * D + j];
      #pragma unroll
      for (int r = 0; r < 32; r++) acc[r] += a_l[r * 125 + c] * w;
    }
    __syncthreads();
  }
  for (int r = 0; r < 32; r++) part[((size_t)vc * D2 + i0 + r) * D + j] = acc[r];
}

__global__ __launch_bounds__(256) void k_mreduce(const float* __restrict__ part,
                                                 float* __restrict__ M) {
  int i = blockIdx.x, j = threadIdx.x;
  float s = 0.f;
  for (int vc = 0; vc < 8; vc++) s += part[((size_t)vc * D2 + i) * D + j];
  M[i * D + j] = s;
}

__global__ __launch_bounds__(256) void k_gemmK256(const float* __restrict__ Am,
                                                  const float* __restrict__ Bm,
                                                  float* __restrict__ C, int I) {
  int r0 = blockIdx.x * 8;
  int tid = threadIdx.x;
  __shared__ float a_l[8][256];
  for (int i = tid; i < 8 * 256; i += 256) a_l[i >> 8][i & 255] = Am[(r0 + (i >> 8)) * 256 + (i & 255)];
  __syncthreads();
  float acc[8] = {0, 0, 0, 0, 0, 0, 0, 0};
  for (int k = 0; k < 256; k++) {
    float bv = Bm[k * 256 + tid];
    #pragma unroll
    for (int r = 0; r < 8; r++) acc[r] += a_l[r][k] * bv;
  }
  for (int r = 0; r < 8; r++) C[(r0 + r) * 256 + tid] = acc[r];
}

__global__ __launch_bounds__(256) void k_vecmat(const float* __restrict__ a,
                                                const float* __restrict__ Bm,
                                                const float* __restrict__ bias,
                                                float* __restrict__ out) {
  int tid = threadIdx.x;
  __shared__ float a_l[256];
  a_l[tid] = a[tid];
  __syncthreads();
  float acc = 0.f;
  for (int k = 0; k < 256; k++) acc += a_l[k] * Bm[k * 256 + tid];
  out[tid] = acc + bias[tid];
}

__global__ __launch_bounds__(256) void k_barinit(unsigned* bars) {
  int i = blockIdx.x * 256 + threadIdx.x;
  if (i < 8192) bars[i] = 0u;
}

// ---------------- chain barrier (32 blocks, flag-array) ----------------

DEV void cbar(unsigned* f, int slot, unsigned e) {
  asm volatile("s_waitcnt vmcnt(0) lgkmcnt(0)" ::: "memory");  // all waves drain their stores
  __syncthreads();
  if (threadIdx.x == 0)
    __hip_atomic_store(&f[slot * 32], e, __ATOMIC_RELAXED, __HIP_MEMORY_SCOPE_AGENT);
  if (threadIdx.x < 64) {
    int s = threadIdx.x & 31;
    unsigned spins = 0;
    for (;;) {
      unsigned v = __hip_atomic_load(&f[s * 32], __ATOMIC_RELAXED, __HIP_MEMORY_SCOPE_AGENT);
      if (__all(v >= e)) break;
      __builtin_amdgcn_s_sleep(1);
      if (++spins > (1u << 25)) break;
    }
  }
  __syncthreads();
}

// ---------------- persistent kernel ----------------

struct PP {
  const float *Wsens, *bs2, *sigbind, *anet, *Wc, *bc, *Wg, *bg, *lng, *lnb, *cw, *iw;
  const float *Wq, *bq, *Wk, *bk, *Wv, *bv, *Wo, *bo, *Wmg, *WoMg, *cvec2, *mlng, *mlnb;
  const float *Wa1, *ba1, *M2, *cvec3, *cvec4, *P, *pW;
  float *agents, *sensbuf, *ubufG, *psumU, *consbuf, *recbuf, *valbuf, *valps;
  float *kvK, *kvV, *hbuf, *modbuf, *Hall;
  unsigned* flags;
};

// LDS layout (floats) — all offsets 16B-aligned
#define A_OFF 0        // [32][260] = 8320
#define ASL_OFF 8320   // [64][16]  = 1024
#define X_OFF 9344     // [64][48]  = 3072  (U1 slice in P3)
#define U_OFF 12416    // [64][16]  = 1024
#define MOD_OFF 13440  // 256
#define CONS_OFF 13696 // 256
#define REC_OFF 13952  // 256
#define VV_OFF 14208   // 256
#define CF_OFF 14464   // 256
#define HL_OFF 14720   // 512
#define STT_OFF 15232  // 256
#define RED_OFF 15488  // 1024
#define K_OFF 16512    // [128][68] = 8704
#define V_OFF 25216    // [128][64] = 8192
#define TOTAL_LDS_F 33408  // 133632 bytes

__global__ __launch_bounds__(512) void k_persist(PP p) {
  extern __shared__ float sm[];
  const int bid = blockIdx.x;
  const int tid = threadIdx.x;
  const int b = bid & 7;       // chain (batch)
  const int slot = bid >> 3;   // 0..31 within chain
  const int ch = slot >> 4;    // G1 channel
  const int i16 = slot & 15;   // G1 16-col slice
  const int d0 = i16 * 16;
  unsigned* flg = p.flags + b * 1024;
  unsigned e = 1;

  float* A_l = sm + A_OFF;
  float* Asl = sm + ASL_OFF;
  float* X_l = sm + X_OFF;
  float* U_l = sm + U_OFF;
  float* MODL = sm + MOD_OFF;
  float* CONSL = sm + CONS_OFF;
  float* RECL = sm + REC_OFF;
  float* VVL = sm + VV_OFF;
  float* CFL = sm + CF_OFF;
  float* HLL = sm + HL_OFF;
  float* STT = sm + STT_OFF;
  float* RED = sm + RED_OFF;
  float* K_l = sm + K_OFF;
  float* V_l = sm + V_OFF;

  // ---------- INIT ----------
  if (tid < 128) cst4(p.agents + b * 16384 + slot * 512 + tid * 4, f4z());
  if (tid < 4) {
    int c = slot * 8 + tid * 2;
    int o = (b * 128) * 256 + c;
    float m0 = p.P[o] * (1.f + sigm(p.cvec4[c] + p.pW[o]));
    float m1 = p.P[o + 1] * (1.f + sigm(p.cvec4[c + 1] + p.pW[o + 1]));
    cst2(p.modbuf + b * 256 + c, f32x2{m0, m1});
  }
  cbar(flg, slot, e); e++;

  for (int t = 0; t < T; t++) {
    // ======== P1: stage mod; sens slice (128 cols per block) ========
    {
      if (tid < 64) st4(&MODL[tid * 4], cld4(p.modbuf + b * 256 + tid * 4));
      __syncthreads();
      {
        int cc = tid & 127, ks = tid >> 7;
        int col = slot * 128 + cc;
        float acc = 0.f;
        #pragma unroll 16
        for (int kk = 0; kk < 64; kk++) {
          int k = ks + kk * 4;
          acc += MODL[k] * p.Wsens[k * 4096 + col];
        }
        RED[ks * 128 + cc] = acc;
      }
      __syncthreads();
      if (tid < 32) {
        f32x4 sv;
        #pragma unroll
        for (int j = 0; j < 4; j++) {
          int c4 = tid * 4 + j, col = slot * 128 + c4;
          float s = RED[c4] + RED[128 + c4] + RED[256 + c4] + RED[384 + c4];
          sv[j] = s * p.sigbind[col] + p.bs2[col];
        }
        cst4(p.sensbuf + b * 4096 + slot * 128 + tid * 4, sv);
      }
    }
    cbar(flg, slot, e); e++;

    // ======== P2: A-stage (2 halves) -> X -> Y -> u -> psums + ch1 u export ========
    {
      for (int half = 0; half < 2; half++) {
        const float* abase = p.agents + b * 16384 + half * 8192;
        f32x4 va, vb, vc2, vd;
        cld4x4(abase + tid * 4, abase + 2048 + tid * 4, abase + 4096 + tid * 4,
               abase + 6144 + tid * 4, va, vb, vc2, vd);
        if (half == 0) {
          f32x4 s0, s1;
          cld4x2(p.sensbuf + b * 4096 + tid * 4, p.sensbuf + b * 4096 + 2048 + tid * 4, s0, s1);
          va = add4(va, s0);
          vb = add4(vb, s1);
        }
        {
          int f0 = tid, f1 = tid + 512, f2 = tid + 1024, f3 = tid + 1536;
          st4(&A_l[(f0 >> 6) * 260 + (f0 & 63) * 4], va);
          st4(&A_l[(f1 >> 6) * 260 + (f1 & 63) * 4], vb);
          st4(&A_l[(f2 >> 6) * 260 + (f2 & 63) * 4], vc2);
          st4(&A_l[(f3 >> 6) * 260 + (f3 & 63) * 4], vd);
        }
        __syncthreads();
        {
          int r = tid >> 4, dc = tid & 15;
          Asl[(half * 32 + r) * 16 + dc] = A_l[r * 260 + d0 + dc];
        }
        {
          int r = tid >> 4, dq = (tid >> 2) & 3, ks = tid & 3;
          f32x4 ac = f4z(), ag0 = f4z(), ag1 = f4z();
          const float* wc = p.Wc + ch * 65536 + d0 + dq * 4;
          const float* wg0 = p.Wg + ch * 131072 + d0 + dq * 4;
          const float* wg1 = wg0 + 65536;
          #pragma unroll 8
          for (int kk = 0; kk < 64; kk++) {
            int k = ks + kk * 4;
            float a = A_l[r * 260 + k];
            ac = fma4(a, ld4(wc + k * 256), ac);
            ag0 = fma4(a, ld4(wg0 + k * 256), ag0);
            ag1 = fma4(a, ld4(wg1 + k * 256), ag1);
          }
          ac = add4(ac, shflx4(ac, 1)); ag0 = add4(ag0, shflx4(ag0, 1)); ag1 = add4(ag1, shflx4(ag1, 1));
          ac = add4(ac, shflx4(ac, 2)); ag0 = add4(ag0, shflx4(ag0, 2)); ag1 = add4(ag1, shflx4(ag1, 2));
          if (ks == 0) {
            int rr = half * 32 + r;
            st4(&X_l[rr * 48 + dq * 4], ac);
            st4(&X_l[rr * 48 + 16 + dq * 4], ag0);
            st4(&X_l[rr * 48 + 32 + dq * 4], ag1);
          }
        }
        __syncthreads();
      }
      // Y + u
      {
        int r = tid >> 3, dq = (tid >> 1) & 3, js = tid & 1;
        f32x4 yc = f4z(), yg = f4z();
        const float* an = p.anet + ch * 4096 + r * 64;
        #pragma unroll 8
        for (int jj = 0; jj < 32; jj++) {
          int j = js + jj * 2;
          float a = an[j];
          yc = fma4(a, ld4(&X_l[j * 48 + dq * 4]), yc);
          yg = fma4(a, ld4(&X_l[j * 48 + 32 + dq * 4]), yg);
        }
        yc = add4(yc, shflx4(yc, 1));
        yg = add4(yg, shflx4(yg, 1));
        float su = 0.f, sq = 0.f;
        if (js == 0) {
          int c0g = d0 + dq * 4;
          f32x4 xg0 = ld4(&X_l[r * 48 + 16 + dq * 4]);
          f32x4 av = ld4(&Asl[r * 16 + dq * 4]);
          f32x4 bc4 = ld4(p.bc + ch * 256 + c0g);
          f32x4 bg4 = ld4(p.bg + ch * 256 + c0g);
          f32x4 uu;
          #pragma unroll
          for (int q = 0; q < 4; q++) {
            float g = sigm(xg0[q] + yg[q] + bg4[q]);
            float cnd = geluf(yc[q] + bc4[q]);
            uu[q] = g * cnd + (1.f - g) * av[q];
          }
          st4(&U_l[r * 16 + dq * 4], uu);
          su = uu.x + uu.y + uu.z + uu.w;
          sq = uu.x * uu.x + uu.y * uu.y + uu.z * uu.z + uu.w * uu.w;
        }
        su += __shfl_xor(su, 2, 64); sq += __shfl_xor(sq, 2, 64);
        su += __shfl_xor(su, 4, 64); sq += __shfl_xor(sq, 4, 64);
        if ((tid & 7) == 0)
          cst2(p.psumU + ((b * 2 + ch) * 64 + r) * 32 + i16 * 2, f32x2{su, sq});
      }
      __syncthreads();
      if (ch == 1 && tid < 256)
        cst4(p.ubufG + (b * 16 + i16) * 1024 + tid * 4, ld4(&U_l[tid * 4]));
    }
    cbar(flg, slot, e); e++;

    // ======== P3 (ch0 slots): LN stats, mix -> agents + cons ========
    if (ch == 0) {
      if (tid < 256) st4(&X_l[tid * 4], cld4(p.ubufG + (b * 16 + i16) * 1024 + tid * 4));
      if (tid < 128) {
        int ch2 = tid >> 6, r = tid & 63;
        const float* ps = p.psumU + ((b * 2 + ch2) * 64 + r) * 32;
        f32x4 q0, q1, q2, q3, q4, q5, q6, q7;
        cld4x4(ps, ps + 4, ps + 8, ps + 12, q0, q1, q2, q3);
        cld4x4(ps + 16, ps + 20, ps + 24, ps + 28, q4, q5, q6, q7);
        float s = q0.x + q0.z + q1.x + q1.z + q2.x + q2.z + q3.x + q3.z +
                  q4.x + q4.z + q5.x + q5.z + q6.x + q6.z + q7.x + q7.z;
        float q = q0.y + q0.w + q1.y + q1.w + q2.y + q2.w + q3.y + q3.w +
                  q4.y + q4.w + q5.y + q5.w + q6.y + q6.w + q7.y + q7.w;
        float mn = s * (1.f / 256.f), var = q * (1.f / 256.f) - mn * mn;
        STT[(ch2 * 64 + r) * 2] = mn;
        STT[(ch2 * 64 + r) * 2 + 1] = rsqrtf(var + 1e-5f);
      }
      __syncthreads();
      {
        float cw0 = p.cw[0], cw1 = p.cw[1];
        int r = tid >> 3, pp2 = tid & 7;
        int c0g = d0 + pp2 * 2;
        float m0 = STT[r * 2], rs0 = STT[r * 2 + 1];
        float m1 = STT[128 + r * 2], rs1 = STT[128 + r * 2 + 1];
        float u0a = U_l[r * 16 + pp2 * 2], u0b = U_l[r * 16 + pp2 * 2 + 1];
        float u1a = X_l[r * 16 + pp2 * 2], u1b = X_l[r * 16 + pp2 * 2 + 1];
        float na = cw0 * ((u0a - m0) * rs0 * p.lng[c0g] + p.lnb[c0g]) +
                   cw1 * ((u1a - m1) * rs1 * p.lng[256 + c0g] + p.lnb[256 + c0g]);
        float nb = cw0 * ((u0b - m0) * rs0 * p.lng[c0g + 1] + p.lnb[c0g + 1]) +
                   cw1 * ((u1b - m1) * rs1 * p.lng[256 + c0g + 1] + p.lnb[256 + c0g + 1]);
        cst2(p.agents + (b * 64 + r) * 256 + c0g, f32x2{na, nb});
        float iwr = p.iw[r];
        float pa = iwr * na, pb = iwr * nb;
        pa += __shfl_xor(pa, 8, 64); pb += __shfl_xor(pb, 8, 64);
        pa += __shfl_xor(pa, 16, 64); pb += __shfl_xor(pb, 16, 64);
        pa += __shfl_xor(pa, 32, 64); pb += __shfl_xor(pb, 32, 64);
        if ((tid & 63) < 8) {
          RED[(tid >> 6) * 8 + (tid & 7)] = pa;
          RED[64 + (tid >> 6) * 8 + (tid & 7)] = pb;
        }
      }
      __syncthreads();
      if (tid < 8) {
        float sa = 0.f, sb = 0.f;
        #pragma unroll
        for (int w = 0; w < 8; w++) { sa += RED[w * 8 + tid]; sb += RED[64 + w * 8 + tid]; }
        cst2(p.consbuf + b * 256 + d0 + tid * 2, f32x2{sa, sb});
      }
    }
    cbar(flg, slot, e); e++;

    // ======== P4 (slots 0-3 = heads): K/V append, q, scores, softmax, rec ========
    if (slot < 4 && t > 0) {
      int h = slot;
      if (tid < 16) st4(&K_l[(t - 1) * 68 + tid * 4], cld4(p.kvK + b * 256 + h * 64 + tid * 4));
      else if (tid < 32) {
        int q2 = tid - 16;
        st4(&V_l[(t - 1) * 64 + q2 * 4], cld4(p.kvV + b * 256 + h * 64 + q2 * 4));
      }
      if (tid < 64) st4(&CONSL[tid * 4], cld4(p.consbuf + b * 256 + tid * 4));
      __syncthreads();
      {
        int c = tid & 63, ks = tid >> 6;
        float acc = 0.f;
        #pragma unroll 8
        for (int kk = 0; kk < 32; kk++) {
          int k = ks + kk * 8;
          acc += CONSL[k] * p.Wq[k * 256 + h * 64 + c];
        }
        RED[ks * 64 + c] = acc;
      }
      __syncthreads();
      if (tid < 64) {
        float qv = p.bq[h * 64 + tid];
        #pragma unroll
        for (int w = 0; w < 8; w++) qv += RED[w * 64 + tid];
        VVL[tid] = qv;
      }
      __syncthreads();
      {
        int s = tid >> 2, ds = tid & 3;
        float acc = 0.f;
        if (s < t) {
          #pragma unroll
          for (int i2 = 0; i2 < 16; i2++) {
            int d = ds * 16 + i2;
            acc += VVL[d] * K_l[s * 68 + d];
          }
        }
        acc += __shfl_xor(acc, 1, 64);
        acc += __shfl_xor(acc, 2, 64);
        if (s < t && ds == 0) RECL[s] = acc * 0.125f;
      }
      __syncthreads();
      if (tid < 128) {
        float v = (tid < t) ? RECL[tid] : -1e30f;
        float m = v;
        #pragma unroll
        for (int o = 1; o < 64; o <<= 1) m = fmaxf(m, __shfl_xor(m, o, 64));
        if ((tid & 63) == 0) STT[tid >> 6] = m;
      }
      __syncthreads();
      if (tid < 128) {
        float m = fmaxf(STT[0], STT[1]);
        float v = (tid < t) ? RECL[tid] : -1e30f;
        float ee = (tid < t) ? expf(v - m) : 0.f;
        float den = ee;
        #pragma unroll
        for (int o = 1; o < 64; o <<= 1) den += __shfl_xor(den, o, 64);
        if ((tid & 63) == 0) STT[2 + (tid >> 6)] = den;
        CFL[tid] = ee;
      }
      __syncthreads();
      if (tid < 128) RECL[tid] = CFL[tid] / (STT[2] + STT[3]);
      __syncthreads();
      {
        int c = tid & 63, ss = tid >> 6;
        float acc = 0.f;
        #pragma unroll
        for (int i2 = 0; i2 < 16; i2++) {
          int s = ss + i2 * 8;
          if (s < t) acc += RECL[s] * V_l[s * 64 + c];
        }
        RED[ss * 64 + c] = acc;
      }
      __syncthreads();
      if (tid < 64) {
        float rv = 0.f;
        #pragma unroll
        for (int w = 0; w < 8; w++) rv += RED[w * 64 + tid];
        CFL[tid] = rv;
      }
      __syncthreads();
      if (tid < 16) cst4(p.recbuf + b * 256 + h * 64 + tid * 4, ld4(&CFL[tid * 4]));
    }
    cbar(flg, slot, e); e++;

    // ======== P5 (slots 8-15): o / mg / val / valps ========
    if (slot >= 8 && slot < 16 && t > 0) {
      int j = slot - 8;
      if (tid < 64) {
        f32x4 r4, c4;
        cld4x2(p.recbuf + b * 256 + tid * 4, p.consbuf + b * 256 + tid * 4, r4, c4);
        st4(&RECL[tid * 4], r4);
        st4(&CONSL[tid * 4], c4);
      }
      __syncthreads();
      {
        int c = tid & 31, ks = tid >> 5;
        float po = 0.f, pm = 0.f;
        #pragma unroll
        for (int kk = 0; kk < 16; kk++) {
          int k = ks + kk * 16;
          float rv = RECL[k], cv = CONSL[k];
          po += rv * p.Wo[k * 256 + j * 32 + c];
          pm += cv * p.Wmg[k * 256 + j * 32 + c] + rv * p.WoMg[k * 256 + j * 32 + c];
        }
        RED[ks * 32 + c] = po;
        RED[512 + ks * 32 + c] = pm;
      }
      __syncthreads();
      if (tid < 32) {
        int col = j * 32 + tid;
        float so = p.bo[col], sm2 = p.cvec2[col];
        #pragma unroll
        for (int k2 = 0; k2 < 16; k2++) { so += RED[k2 * 32 + tid]; sm2 += RED[512 + k2 * 32 + tid]; }
        float mg = sigm(sm2);
        float val = CONSL[col] + mg * so;
        VVL[tid] = val;
        float su = val, sq = val * val;
        #pragma unroll
        for (int o2 = 1; o2 <= 16; o2 <<= 1) { su += __shfl_xor(su, o2, 64); sq += __shfl_xor(sq, o2, 64); }
        if (tid == 0) cst2(p.valps + b * 16 + j * 2, f32x2{su, sq});
      }
      __syncthreads();
      if (tid < 8) cst4(p.valbuf + b * 256 + j * 32 + tid * 4, ld4(&VVL[tid * 4]));
    }
    cbar(flg, slot, e); e++;

    // ======== P6 (slots 16-23): cf (redundant LN) -> K/V -> h ========
    if (slot >= 16 && slot < 24) {
      int jj = slot - 16;
      const float* src = (t > 0) ? p.valbuf : p.consbuf;
      if (tid < 64) st4(&VVL[tid * 4], cld4(src + b * 256 + tid * 4));
      if (t > 0 && tid >= 64 && tid < 68)
        st4(&RED[(tid - 64) * 4], cld4(p.valps + b * 16 + (tid - 64) * 4));
      __syncthreads();
      if (t > 0) {
        if (tid == 0) {
          float s = 0.f, q = 0.f;
          #pragma unroll
          for (int k2 = 0; k2 < 8; k2++) { s += RED[k2 * 2]; q += RED[k2 * 2 + 1]; }
          float mn = s * (1.f / 256.f), var = q * (1.f / 256.f) - mn * mn;
          STT[0] = mn; STT[1] = rsqrtf(var + 1e-5f);
        }
        __syncthreads();
        if (tid < 256) CFL[tid] = (VVL[tid] - STT[0]) * STT[1] * p.mlng[tid] + p.mlnb[tid];
      } else {
        if (tid < 256) CFL[tid] = VVL[tid];
      }
      __syncthreads();
      {
        int c = tid & 31, ks = tid >> 5;
        float pk = 0.f, pv = 0.f;
        #pragma unroll
        for (int kk = 0; kk < 16; kk++) {
          int k = ks + kk * 16;
          float cf = CFL[k];
          pk += cf * p.Wk[k * 256 + jj * 32 + c];
          pv += cf * p.Wv[k * 256 + jj * 32 + c];
        }
        RED[ks * 32 + c] = pk;
        RED[512 + ks * 32 + c] = pv;
      }
      __syncthreads();
      if (tid < 32) {
        int col = jj * 32 + tid;
        float sk = p.bk[col], sv = p.bv[col];
        #pragma unroll
        for (int k2 = 0; k2 < 16; k2++) { sk += RED[k2 * 32 + tid]; sv += RED[512 + k2 * 32 + tid]; }
        VVL[tid] = sk;
        VVL[64 + tid] = sv;
      }
      __syncthreads();
      if (tid < 8) cst4(p.kvK + b * 256 + jj * 32 + tid * 4, ld4(&VVL[tid * 4]));
      else if (tid < 16) cst4(p.kvV + b * 256 + jj * 32 + (tid - 8) * 4, ld4(&VVL[64 + (tid - 8) * 4]));
      __syncthreads();
      {
        int c = tid & 63, ks = tid >> 6;
        float ph = 0.f;
        #pragma unroll 8
        for (int kk = 0; kk < 32; kk++) {
          int k = ks + kk * 8;
          ph += CFL[k] * p.Wa1[k * 512 + jj * 64 + c];
        }
        RED[ks * 64 + c] = ph;
      }
      __syncthreads();
      if (tid < 64) {
        int col = jj * 64 + tid;
        float s = p.ba1[col];
        #pragma unroll
        for (int w = 0; w < 8; w++) s += RED[w * 64 + tid];
        float hv = geluf(s);
        HLL[tid] = hv;
        p.Hall[(size_t)(b * 128 + t) * 512 + col] = hv;  // plain: read post-kernel only
      }
      __syncthreads();
      if (tid < 16) cst4(p.hbuf + b * 512 + jj * 64 + tid * 4, ld4(&HLL[tid * 4]));
    }
    cbar(flg, slot, e); e++;

    // ======== P7 (slots 24-31): fg -> mod ========
    if (slot >= 24 && t < T - 1) {
      int jm = slot - 24;
      if (tid < 128) st4(&HLL[tid * 4], cld4(p.hbuf + b * 512 + tid * 4));
      __syncthreads();
      {
        int c = tid & 31, ks = tid >> 5;
        float pf = 0.f;
        #pragma unroll 8
        for (int kk = 0; kk < 32; kk++) {
          int k = ks + kk * 16;
          pf += HLL[k] * p.M2[k * 256 + jm * 32 + c];
        }
        RED[ks * 32 + c] = pf;
      }
      __syncthreads();
      if (tid < 32) {
        int col = jm * 32 + tid;
        float s = p.cvec3[col];
        #pragma unroll
        for (int k2 = 0; k2 < 16; k2++) s += RED[k2 * 32 + tid];
        int o = (b * 128 + t + 1) * 256 + col;
        VVL[tid] = p.P[o] * (1.f + sigm(s + p.pW[o]));
      }
      __syncthreads();
      if (tid < 8) cst4(p.modbuf + b * 256 + jm * 32 + tid * 4, ld4(&VVL[tid * 4]));
    }
    cbar(flg, slot, e); e++;
  }
}

// ---------------- logits ----------------

__global__ __launch_bounds__(256) void k_logits(const float* __restrict__ Hall,
                                                const float* __restrict__ Wa2,
                                                const float* __restrict__ ba2,
                                                float* __restrict__ out) {
  int rt = blockIdx.y;
  int v = blockIdx.x * 256 + threadIdx.x;
  const float* hrow = Hall + (size_t)rt * 32 * D2;
  float acc[32];
  float bb = ba2[v];
  #pragma unroll
  for (int r = 0; r < 32; r++) acc[r] = bb;
  for (int k = 0; k < D2; k++) {
    float w = Wa2[(size_t)k * V + v];
    #pragma unroll
    for (int r = 0; r < 32; r++) acc[r] += hrow[r * D2 + k] * w;
  }
  for (int r = 0; r < 32; r++) out[(size_t)(rt * 32 + r) * V + v] = acc[r];
}

// ---------------- launcher ----------------

extern "C" void kernel_launch(void* const* d_in, const int* in_sizes, int n_in,
                              void* d_out, int out_size, void* d_ws, size_t ws_size,
                              hipStream_t stream) {
  const int* idx = (const int*)d_in[0];
  const float* emb = (const float*)d_in[1];
  const float* pos = (const float*)d_in[2];
  const float* Wsens = (const float*)d_in[3];
  const float* bsens = (const float*)d_in[4];
  const float* Wfb = (const float*)d_in[5];
  const float* bfb = (const float*)d_in[6];
  const float* Wfg = (const float*)d_in[7];
  const float* bfg = (const float*)d_in[8];
  const float* bind = (const float*)d_in[9];
  const float* anet = (const float*)d_in[10];
  const float* Wg = (const float*)d_in[11];
  const float* bg = (const float*)d_in[12];
  const float* Wc = (const float*)d_in[13];
  const float* bc = (const float*)d_in[14];
  const float* lng = (const float*)d_in[15];
  const float* lnb = (const float*)d_in[16];
  const float* cmix = (const float*)d_in[17];
  const float* aimp = (const float*)d_in[18];
  const float* Wq = (const float*)d_in[19];
  const float* bq = (const float*)d_in[20];
  const float* Wk = (const float*)d_in[21];
  const float* bk = (const float*)d_in[22];
  const float* Wv = (const float*)d_in[23];
  const float* bv = (const float*)d_in[24];
  const float* Wo = (const float*)d_in[25];
  const float* bo = (const float*)d_in[26];
  const float* Wmg = (const float*)d_in[27];
  const float* bmg = (const float*)d_in[28];
  const float* mlng = (const float*)d_in[29];
  const float* mlnb = (const float*)d_in[30];
  const float* Wa1 = (const float*)d_in[31];
  const float* ba1 = (const float*)d_in[32];
  const float* Wa2 = (const float*)d_in[33];
  const float* ba2 = (const float*)d_in[34];

  float* ws = (float*)d_ws;
  float* M2 = ws + 0;              // 131072
  float* WoMg = ws + 131072;       // 65536
  float* cvec = ws + 196608;       // 256
  float* cvec2 = ws + 196864;      // 256
  float* cvec3 = ws + 197120;      // 256
  float* cvec4 = ws + 197376;      // 256
  float* iw = ws + 197632;         // 64
  float* cwb = ws + 197696;        // 64
  float* sigbind = ws + 197760;    // 4096
  float* bs2 = ws + 201856;        // 4096
  float* P = ws + 205952;          // 262144
  float* pW = ws + 468096;         // 262144
  float* agents = ws + 730240;     // 131072
  float* sensbuf = ws + 861312;    // 32768
  float* ubufG = ws + 894080;      // 131072
  float* psumU = ws + 1025152;     // 32768
  float* consbuf = ws + 1057920;   // 2048
  float* recbuf = ws + 1059968;    // 2048
  float* valbuf = ws + 1062016;    // 2048
  float* valps = ws + 1064064;     // 128
  float* kvK = ws + 1064192;       // 2048
  float* kvV = ws + 1066240;       // 2048
  float* hbuf = ws + 1068288;      // 4096
  float* modbuf = ws + 1072384;    // 2048
  float* Hall = ws + 1074432;      // 524288
  float* M = ws + 1598720;         // 131072
  float* Mpart = ws + 1729792;     // 1048576
  float* cvpart = ws + 2778368;    // 32000
  unsigned* flags = (unsigned*)(ws + 2810368);  // 8192 u32

  k_setup<<<1, 256, 0, stream>>>(aimp, cmix, bind, bsens, iw, cwb, sigbind, bs2);
  k_percepts<<<dim3((B * T * D + 255) / 256), 256, 0, stream>>>(idx, emb, pos, P);
  k_cvec_part<<<125, 256, 0, stream>>>(Wfb, ba2, cvpart);
  k_cvec_red<<<1, 256, 0, stream>>>(cvpart, bfb, cvec);
  k_mpart<<<dim3(8, 16), 256, 0, stream>>>(Wa2, Wfb, Mpart);
  k_mreduce<<<512, 256, 0, stream>>>(Mpart, M);
  k_gemmK256<<<64, 256, 0, stream>>>(M, Wfg, M2, 512);
  k_gemmK256<<<32, 256, 0, stream>>>(Wo, Wmg + 65536, WoMg, 256);
  k_gemmK256<<<128, 256, 0, stream>>>(P, Wfg + 65536, pW, 1024);
  k_vecmat<<<1, 256, 0, stream>>>(bo, Wmg + 65536, bmg, cvec2);
  k_vecmat<<<1, 256, 0, stream>>>(cvec, Wfg, bfg, cvec3);
  k_vecmat<<<1, 256, 0, stream>>>(bfb, Wfg, bfg, cvec4);
  k_barinit<<<32, 256, 0, stream>>>(flags);

  PP prm;
  prm.Wsens = Wsens; prm.bs2 = bs2; prm.sigbind = sigbind; prm.anet = anet;
  prm.Wc = Wc; prm.bc = bc; prm.Wg = Wg; prm.bg = bg; prm.lng = lng; prm.lnb = lnb;
  prm.cw = cwb; prm.iw = iw; prm.Wq = Wq; prm.bq = bq; prm.Wk = Wk; prm.bk = bk;
  prm.Wv = Wv; prm.bv = bv; prm.Wo = Wo; prm.bo = bo; prm.Wmg = Wmg; prm.WoMg = WoMg;
  prm.cvec2 = cvec2; prm.mlng = mlng; prm.mlnb = mlnb; prm.Wa1 = Wa1; prm.ba1 = ba1;
  prm.M2 = M2; prm.cvec3 = cvec3; prm.cvec4 = cvec4; prm.P = P; prm.pW = pW;
  prm.agents = agents; prm.sensbuf = sensbuf; prm.ubufG = ubufG; prm.psumU = psumU;
  prm.consbuf = consbuf; prm.recbuf = recbuf; prm.valbuf = valbuf; prm.valps = valps;
  prm.kvK = kvK; prm.kvV = kvV; prm.hbuf = hbuf; prm.modbuf = modbuf;
  prm.Hall = Hall; prm.flags = flags;

  hipFuncSetAttribute((const void*)k_persist, hipFuncAttributeMaxDynamicSharedMemorySize,
                      TOTAL_LDS_F * 4);

  void* args[] = {&prm};
  hipLaunchCooperativeKernel((void*)k_persist, dim3(256), dim3(512), args,
                             TOTAL_LDS_F * 4, stream);

  k_logits<<<dim3(125, 32), 256, 0, stream>>>(Hall, Wa2, ba2, (float*)d_out);
}